// Round 1
// 202.835 us; speedup vs baseline: 1.0123x; 1.0123x over previous
//
#include <hip/hip_runtime.h>

#define BATCH    8192
#define CTX      32
#define ROUTES   24
#define EDIM     128
#define NSLICE   24
#define WPB      4
#define NBLOCKS  (BATCH / WPB)

// Packed multi-value wave reduction: 24 per-lane partials, each needing a
// full 64-lane sum. Fold (shfl_xor) + pack (halve live value count) each
// level: 24+12+6+3+2+1 = 48 cross-lane ops instead of 24*6 = 144, and all
// folds within a level are independent (pipelined, no serial chains).
// Lane l ends holding the full sum of value
//   v(l) = bit5(l) | bit4(l)<<1 | bit3(l)<<2 | bit2(l)<<3 | bit1(l)<<4
// (lanes l and l^1 hold the same value).
__device__ __forceinline__ float packed_sum24(const float (&p)[24], const int lane)
{
    float c[12];
    #pragma unroll
    for (int i = 0; i < 12; ++i) {
        const float e0 = p[2*i]   + __shfl_xor(p[2*i],   32);
        const float e1 = p[2*i+1] + __shfl_xor(p[2*i+1], 32);
        c[i] = (lane & 32) ? e1 : e0;
    }
    float d[6];
    #pragma unroll
    for (int i = 0; i < 6; ++i) {
        const float e0 = c[2*i]   + __shfl_xor(c[2*i],   16);
        const float e1 = c[2*i+1] + __shfl_xor(c[2*i+1], 16);
        d[i] = (lane & 16) ? e1 : e0;
    }
    float e[3];
    #pragma unroll
    for (int i = 0; i < 3; ++i) {
        const float e0 = d[2*i]   + __shfl_xor(d[2*i],   8);
        const float e1 = d[2*i+1] + __shfl_xor(d[2*i+1], 8);
        e[i] = (lane & 8) ? e1 : e0;
    }
    // values 24..31 are implicit zeros
    const float f0a = e[0] + __shfl_xor(e[0], 4);
    const float f0b = e[1] + __shfl_xor(e[1], 4);
    const float f0  = (lane & 4) ? f0b : f0a;
    const float f1  = (lane & 4) ? 0.f : (e[2] + __shfl_xor(e[2], 4));
    const float g0 = f0 + __shfl_xor(f0, 2);
    const float g1 = f1 + __shfl_xor(f1, 2);
    float g = (lane & 2) ? g1 : g0;
    g += __shfl_xor(g, 1);
    return g;
}

// One wave per batch row. Every embedding row is read by the WHOLE wave as
// 64 x float2 (512B coalesced) from a wave-uniform (SGPR) base: indices are
// s_load'ed, so gathers have zero VALU address math and no ds_bpermute
// broadcasts. All gathers issue back-to-back (deep MLP); all dot reductions
// are deferred into two packed trees at the end.
__global__ __launch_bounds__(256, 4) void tale_fused(
    const int* __restrict__ context,            // (B, C)
    const int* __restrict__ route,              // (B, R)
    const int* __restrict__ lr,                 // (B, R)
    const int* __restrict__ slice_idx,          // (B,)
    const float* __restrict__ input_embed,      // (NUM_LOC, E)
    const float* __restrict__ inner_node_embed, // (NUM_INNER+1, E)
    const float* __restrict__ slice_node_embed, // (NSLICE, E)
    float* __restrict__ out)
{
    const int tid  = threadIdx.x;
    const int lane = tid & 63;
    const int w    = tid >> 6;
    const int b    = __builtin_amdgcn_readfirstlane(blockIdx.x * WPB + w);

    __shared__ float bs[WPB];

    const int voff = lane << 1;   // this lane owns dims 2*lane, 2*lane+1

    // lane -> value mapping of the packed reduction tree
    const int v = ((lane >> 5) & 1) | (((lane >> 4) & 1) << 1) |
                  (((lane >> 3) & 1) << 2) | (((lane >> 2) & 1) << 3) |
                  (((lane >> 1) & 1) << 4);
    const bool vvalid = (v < ROUTES);
    const int  vcl    = vvalid ? v : 0;

    // per-lane route id / lr flag for the dot this lane will own
    const int rv = route[b * ROUTES + vcl];
    const int lv = lr[b * ROUTES + vcl];
    const int si = slice_idx[b];

    // ---- context embedding sum: 32 independent row reads, 4 acc chains ----
    float a0x=0.f,a0y=0.f,a1x=0.f,a1y=0.f,a2x=0.f,a2y=0.f,a3x=0.f,a3y=0.f;
    #pragma unroll
    for (int i = 0; i < CTX; i += 4) {
        const int i0 = context[b * CTX + i + 0];   // uniform -> s_load
        const int i1 = context[b * CTX + i + 1];
        const int i2 = context[b * CTX + i + 2];
        const int i3 = context[b * CTX + i + 3];
        const float2 r0 = *reinterpret_cast<const float2*>(input_embed + (size_t)i0 * EDIM + voff);
        const float2 r1 = *reinterpret_cast<const float2*>(input_embed + (size_t)i1 * EDIM + voff);
        const float2 r2 = *reinterpret_cast<const float2*>(input_embed + (size_t)i2 * EDIM + voff);
        const float2 r3 = *reinterpret_cast<const float2*>(input_embed + (size_t)i3 * EDIM + voff);
        a0x += r0.x; a0y += r0.y;
        a1x += r1.x; a1y += r1.y;
        a2x += r2.x; a2y += r2.y;
        a3x += r3.x; a3y += r3.y;
    }
    const float ax = (a0x + a1x) + (a2x + a3x);
    const float ay = (a0y + a1y) + (a2y + a3y);

    // ---- route dot partials: 24 independent gathers, reductions deferred ----
    float p[24];
    #pragma unroll
    for (int r = 0; r < ROUTES; ++r) {
        const int idx = route[b * ROUTES + r];     // uniform -> s_load
        const float2 t = *reinterpret_cast<const float2*>(
            inner_node_embed + (size_t)idx * EDIM + voff);
        p[r] = t.x * ax + t.y * ay;
    }
    const float dotv = packed_sum24(p, lane);      // lane holds dot v(l)

    // ---- slice logit partials (12KB table, L1-resident) ----
    float q[24];
    #pragma unroll
    for (int s = 0; s < NSLICE; ++s) {
        const float2 t = *reinterpret_cast<const float2*>(
            slice_node_embed + s * EDIM + voff);
        q[s] = t.x * ax + t.y * ay;
    }
    const float logv = packed_sum24(q, lane);      // lane holds logit v(l)

    // ---- route product over the 24 hidden factors ----
    const float sg = 1.f / (1.f + __expf(-dotv));
    float h = lv ? sg : (1.f - sg);
    // dedupe lane pairs (l, l^1 hold the same value), padding lanes, route==0
    if (!vvalid || rv == 0 || (lane & 1)) h = 1.f;
    h *= __shfl_xor(h, 32);
    h *= __shfl_xor(h, 16);
    h *= __shfl_xor(h, 8);
    h *= __shfl_xor(h, 4);
    h *= __shfl_xor(h, 2);
    h *= __shfl_xor(h, 1);
    const float prodv = h;                         // uniform across wave

    // ---- slice softmax over the 24 logits ----
    float ml = vvalid ? logv : -3.0e38f;
    ml = fmaxf(ml, __shfl_xor(ml, 32));
    ml = fmaxf(ml, __shfl_xor(ml, 16));
    ml = fmaxf(ml, __shfl_xor(ml, 8));
    ml = fmaxf(ml, __shfl_xor(ml, 4));
    ml = fmaxf(ml, __shfl_xor(ml, 2));
    ml = fmaxf(ml, __shfl_xor(ml, 1));             // uniform max
    float ev = (vvalid && !(lane & 1)) ? __expf(logv - ml) : 0.f;
    float den = ev;
    den += __shfl_xor(den, 32);
    den += __shfl_xor(den, 16);
    den += __shfl_xor(den, 8);
    den += __shfl_xor(den, 4);
    den += __shfl_xor(den, 2);
    den += __shfl_xor(den, 1);                     // uniform denominator
    // lane holding slice si: inverse of v(l) mapping (even lane, bit0=0)
    const int lsel = (((si >> 4) & 1) << 1) | (((si >> 3) & 1) << 2) |
                     (((si >> 2) & 1) << 3) | (((si >> 1) & 1) << 4) |
                     ((si & 1) << 5);
    const float esel = __shfl(ev, lsel);
    const float pr = (esel / den) * prodv;

    if (lane == 0) bs[w] = pr;
    __syncthreads();
    if (tid == 0) {
        const float s = (bs[0] + bs[1]) + (bs[2] + bs[3]);
        // out = sum over blocks of (1/NBLOCKS - blockSum/B) = 1 - mean
        atomicAdd(out, 1.0f / NBLOCKS - s * (1.0f / BATCH));
    }
}

extern "C" void kernel_launch(void* const* d_in, const int* in_sizes, int n_in,
                              void* d_out, int out_size, void* d_ws, size_t ws_size,
                              hipStream_t stream)
{
    const int*   context          = (const int*)  d_in[0];
    const int*   route            = (const int*)  d_in[1];
    const int*   lr               = (const int*)  d_in[2];
    const int*   slice_idx        = (const int*)  d_in[3];
    const float* input_embed      = (const float*)d_in[4];
    const float* inner_node_embed = (const float*)d_in[5];
    const float* slice_node_embed = (const float*)d_in[6];
    float* out = (float*)d_out;

    // d_out is poisoned 0xAA before every launch; zero it, then blocks
    // atomic-accumulate (1/NBLOCKS - blockSum/B) so the final value is 1-mean.
    hipMemsetAsync(out, 0, sizeof(float), stream);

    tale_fused<<<NBLOCKS, 64 * WPB, 0, stream>>>(
        context, route, lr, slice_idx,
        input_embed, inner_node_embed, slice_node_embed, out);
}

// Round 2
// 200.989 us; speedup vs baseline: 1.0216x; 1.0092x over previous
//
#include <hip/hip_runtime.h>

#define BATCH    8192
#define CTX      32
#define ROUTES   24
#define EDIM     128
#define NSLICE   24
#define WPB      4
#define NBLOCKS  (BATCH / WPB)

__device__ __forceinline__ float dot4(const float4 a, const float4 b)
{
    return a.x * b.x + a.y * b.y + a.z * b.z + a.w * b.w;
}

// Packed tree over 12 per-lane partials, reductions confined to a 32-lane
// half (all xor masks <= 16). Fold+pack: 12+6+3+2+1 = 24 cross-lane ops.
// Lane `sub` ends holding the full half-sum of value
//   v = ((sub>>4)&1) | ((sub>>3)&1)<<1 | ((sub>>2)&1)<<2 | ((sub>>1)&1)<<3
// (lanes sub and sub^1 hold the same value; v >= 12 slots are zero-filled).
__device__ __forceinline__ float packed_sum12(const float (&p)[12], const int sub)
{
    float c[6];
    #pragma unroll
    for (int i = 0; i < 6; ++i) {
        const float e0 = p[2*i]   + __shfl_xor(p[2*i],   16);
        const float e1 = p[2*i+1] + __shfl_xor(p[2*i+1], 16);
        c[i] = (sub & 16) ? e1 : e0;
    }
    float d[3];
    #pragma unroll
    for (int i = 0; i < 3; ++i) {
        const float e0 = c[2*i]   + __shfl_xor(c[2*i],   8);
        const float e1 = c[2*i+1] + __shfl_xor(c[2*i+1], 8);
        d[i] = (sub & 8) ? e1 : e0;
    }
    const float e0a = d[0] + __shfl_xor(d[0], 4);
    const float e0b = d[1] + __shfl_xor(d[1], 4);
    const float e0  = (sub & 4) ? e0b : e0a;
    const float e1  = (sub & 4) ? 0.f : (d[2] + __shfl_xor(d[2], 4));
    const float f0  = e0 + __shfl_xor(e0, 2);
    const float f1  = e1 + __shfl_xor(e1, 2);
    float g = (sub & 2) ? f1 : f0;
    g += __shfl_xor(g, 1);
    return g;
}

// One wave per batch row. Each load instruction fetches a ROW PAIR: lanes
// 0-31 read row 2i, lanes 32-63 read row 2i+1 (float4/lane -> 1KB/instr).
// 40 vector loads per wave instead of 80; p/q partial arrays are 12 long;
// all reduction trees are 5-level (within a 32-lane half). Indices are
// SGPR-resident (s_loads hoisted to entry); the only per-load VALU work is
// one v_cndmask half-select + address math. Lean registers (<64 VGPR) so
// 8 waves/SIMD stay resident: the point of this version is raw
// memory-level parallelism (32 waves/CU x ~8 rows in flight each).
__global__ __launch_bounds__(256, 8) void tale_fused(
    const int* __restrict__ context,            // (B, C)
    const int* __restrict__ route,              // (B, R)
    const int* __restrict__ lr,                 // (B, R)
    const int* __restrict__ slice_idx,          // (B,)
    const float* __restrict__ input_embed,      // (NUM_LOC, E)
    const float* __restrict__ inner_node_embed, // (NUM_INNER+1, E)
    const float* __restrict__ slice_node_embed, // (NSLICE, E)
    float* __restrict__ out)
{
    const int tid  = threadIdx.x;
    const int lane = tid & 63;
    const int half = lane >> 5;     // row-pair selector
    const int sub  = lane & 31;     // owns dims 4*sub .. 4*sub+3
    const int w    = tid >> 6;
    const int b    = __builtin_amdgcn_readfirstlane(blockIdx.x * WPB + w);

    __shared__ float bs[WPB];

    // packed-tree value owned by this lane (within its half)
    const int v = ((sub >> 4) & 1) | (((sub >> 3) & 1) << 1) |
                  (((sub >> 2) & 1) << 2) | (((sub >> 1) & 1) << 3);
    const bool vvalid = (v < 12);
    const int  d      = 2 * v + half;       // dot / logit index in [0,24)
    const int  dcl    = vvalid ? d : 0;

    // per-lane route id / lr flag for the dot this lane will own (gather)
    const int rv  = route[b * ROUTES + dcl];
    const int lvv = lr[b * ROUTES + dcl];
    const int si  = slice_idx[b];

    // ---- context embedding sum: 16 row-pair loads, 2 acc chains ----
    float4 acc0 = make_float4(0.f, 0.f, 0.f, 0.f);
    float4 acc1 = make_float4(0.f, 0.f, 0.f, 0.f);
    #pragma unroll
    for (int i = 0; i < 16; i += 2) {
        const int a_lo = context[b * CTX + 2*i + 0];   // SGPR
        const int a_hi = context[b * CTX + 2*i + 1];
        const int b_lo = context[b * CTX + 2*i + 2];
        const int b_hi = context[b * CTX + 2*i + 3];
        const int ia = half ? a_hi : a_lo;             // v_cndmask
        const int ib = half ? b_hi : b_lo;
        const float4 ra = *reinterpret_cast<const float4*>(
            input_embed + (size_t)ia * EDIM + (sub << 2));
        const float4 rb = *reinterpret_cast<const float4*>(
            input_embed + (size_t)ib * EDIM + (sub << 2));
        acc0.x += ra.x; acc0.y += ra.y; acc0.z += ra.z; acc0.w += ra.w;
        acc1.x += rb.x; acc1.y += rb.y; acc1.z += rb.z; acc1.w += rb.w;
    }
    float4 acc = make_float4(acc0.x + acc1.x, acc0.y + acc1.y,
                             acc0.z + acc1.z, acc0.w + acc1.w);
    // combine even-row (lower half) and odd-row (upper half) partial sums
    acc.x += __shfl_xor(acc.x, 32);
    acc.y += __shfl_xor(acc.y, 32);
    acc.z += __shfl_xor(acc.z, 32);
    acc.w += __shfl_xor(acc.w, 32);
    // lane now holds ctx[4*sub .. 4*sub+3]

    // ---- route dot partials: 12 row-pair gathers, reductions deferred ----
    float p[12];
    #pragma unroll
    for (int i = 0; i < 12; ++i) {
        const int i_lo = route[b * ROUTES + 2*i + 0];  // SGPR
        const int i_hi = route[b * ROUTES + 2*i + 1];
        const int idx  = half ? i_hi : i_lo;           // v_cndmask
        const float4 t = *reinterpret_cast<const float4*>(
            inner_node_embed + (size_t)idx * EDIM + (sub << 2));
        p[i] = dot4(t, acc);                           // partial of dot 2i+half
    }
    const float dotv = packed_sum12(p, sub);           // dot d = 2v+half

    // ---- route product over the 24 hidden factors ----
    const float sg = 1.f / (1.f + __expf(-dotv));
    float h = lvv ? sg : (1.f - sg);
    // dedupe lane pairs (sub, sub^1), invalid slots, padded routes
    if (!vvalid || rv == 0 || (sub & 1)) h = 1.f;
    h *= __shfl_xor(h, 16);
    h *= __shfl_xor(h, 8);
    h *= __shfl_xor(h, 4);
    h *= __shfl_xor(h, 2);
    h *= __shfl_xor(h, 1);
    h *= __shfl_xor(h, 32);
    const float prodv = h;                             // uniform across wave

    // ---- slice logit partials (12KB table, L1-resident) ----
    float q[12];
    #pragma unroll
    for (int i = 0; i < 12; ++i) {
        const float4 t = *reinterpret_cast<const float4*>(
            slice_node_embed + (2*i + half) * EDIM + (sub << 2));
        q[i] = dot4(t, acc);                           // partial of logit 2i+half
    }
    const float logv = packed_sum12(q, sub);           // logit d = 2v+half

    // ---- slice softmax over the 24 logits ----
    float ml = vvalid ? logv : -3.0e38f;
    ml = fmaxf(ml, __shfl_xor(ml, 16));
    ml = fmaxf(ml, __shfl_xor(ml, 8));
    ml = fmaxf(ml, __shfl_xor(ml, 4));
    ml = fmaxf(ml, __shfl_xor(ml, 2));
    ml = fmaxf(ml, __shfl_xor(ml, 1));
    ml = fmaxf(ml, __shfl_xor(ml, 32));                // uniform max
    const float ev = (vvalid && !(sub & 1)) ? __expf(logv - ml) : 0.f;
    float den = ev;
    den += __shfl_xor(den, 16);
    den += __shfl_xor(den, 8);
    den += __shfl_xor(den, 4);
    den += __shfl_xor(den, 2);
    den += __shfl_xor(den, 1);
    den += __shfl_xor(den, 32);                        // uniform denominator
    // lane holding slice si: v = si>>1 (even sub), half = si&1
    const int vt   = si >> 1;
    const int lsel = ((si & 1) << 5) | ((vt & 1) << 4) | (((vt >> 1) & 1) << 3) |
                     (((vt >> 2) & 1) << 2) | (((vt >> 3) & 1) << 1);
    const float esel = __shfl(ev, lsel);
    const float pr = (esel / den) * prodv;

    if (lane == 0) bs[w] = pr;
    __syncthreads();
    if (tid == 0) {
        const float s = (bs[0] + bs[1]) + (bs[2] + bs[3]);
        // out = sum over blocks of (1/NBLOCKS - blockSum/B) = 1 - mean
        atomicAdd(out, 1.0f / NBLOCKS - s * (1.0f / BATCH));
    }
}

extern "C" void kernel_launch(void* const* d_in, const int* in_sizes, int n_in,
                              void* d_out, int out_size, void* d_ws, size_t ws_size,
                              hipStream_t stream)
{
    const int*   context          = (const int*)  d_in[0];
    const int*   route            = (const int*)  d_in[1];
    const int*   lr               = (const int*)  d_in[2];
    const int*   slice_idx        = (const int*)  d_in[3];
    const float* input_embed      = (const float*)d_in[4];
    const float* inner_node_embed = (const float*)d_in[5];
    const float* slice_node_embed = (const float*)d_in[6];
    float* out = (float*)d_out;

    // d_out is poisoned 0xAA before every launch; zero it, then blocks
    // atomic-accumulate (1/NBLOCKS - blockSum/B) so the final value is 1-mean.
    hipMemsetAsync(out, 0, sizeof(float), stream);

    tale_fused<<<NBLOCKS, 64 * WPB, 0, stream>>>(
        context, route, lr, slice_idx,
        input_embed, inner_node_embed, slice_node_embed, out);
}